// Round 11
// baseline (72.254 us; speedup 1.0000x reference)
//
#include <hip/hip_runtime.h>
#include <hip/hip_bf16.h>

#define IN_F   4096
#define OUT_F  4096
#define BATCH  256

#define EW_BLOCKS  4096
#define EW_THREADS 256
#define EW_ITERS   4   // EW_BLOCKS*EW_THREADS*4*EW_ITERS == OUT_F*IN_F

#define KSPLIT 4
#define KLEN   (IN_F / KSPLIT)   // 1024

typedef __attribute__((ext_vector_type(8))) short shortx8;    // 8 bf16
typedef __attribute__((ext_vector_type(4))) float floatx4;
typedef __attribute__((ext_vector_type(4))) unsigned short ushortx4;

typedef __attribute__((address_space(1))) const void GlbV;
typedef __attribute__((address_space(3))) void LdsV;

static __device__ __forceinline__ ushort f2bf(float f) {
    union { float f; unsigned int u; } v; v.f = f;
    unsigned int u = v.u;
    u += 0x7FFFu + ((u >> 16) & 1u);   // RNE
    return (ushort)(u >> 16);
}

static __device__ __forceinline__ float softplus_fast(float x) {
    return (x > 15.f) ? x : __logf(1.f + __expf(x));
}

#define KL_C0 (-2.80258509299f)   // log(0.1) - 0.5  (prior_sigma=0.1, prior_mu=0: spec constants)

// ---------------- Kernel 1: weight sample (bf16) + KL partial sums -----------
// Inline-asm load block: 12 global_load_dwordx4 (NT) issued back-to-back with
// ONE vmcnt(0) wait. The compiler cannot serialize it -> true MLP-12 per wave
// (R2/R4/R10 source-level attempts were all sunk by the register allocator).
__global__ __launch_bounds__(256) void ew_kernel(
    const float* __restrict__ mu, const float* __restrict__ rho,
    const float* __restrict__ eps,
    ushort* __restrict__ wbf, float* __restrict__ partials)
{
    const int t = blockIdx.x * EW_THREADS + threadIdx.x;
    const int STRIDE = EW_BLOCKS * EW_THREADS;

    const floatx4* m0p = ((const floatx4*)mu)  + t;
    const floatx4* m1p = m0p + STRIDE;
    const floatx4* m2p = m0p + 2 * STRIDE;
    const floatx4* m3p = m0p + 3 * STRIDE;
    const floatx4* r0p = ((const floatx4*)rho) + t;
    const floatx4* r1p = r0p + STRIDE;
    const floatx4* r2p = r0p + 2 * STRIDE;
    const floatx4* r3p = r0p + 3 * STRIDE;
    const floatx4* e0p = ((const floatx4*)eps) + t;
    const floatx4* e1p = e0p + STRIDE;
    const floatx4* e2p = e0p + 2 * STRIDE;
    const floatx4* e3p = e0p + 3 * STRIDE;

    floatx4 m[EW_ITERS], r[EW_ITERS], e[EW_ITERS];
    asm volatile(
        "global_load_dwordx4 %0, %12, off nt\n\t"
        "global_load_dwordx4 %1, %13, off nt\n\t"
        "global_load_dwordx4 %2, %14, off nt\n\t"
        "global_load_dwordx4 %3, %15, off nt\n\t"
        "global_load_dwordx4 %4, %16, off nt\n\t"
        "global_load_dwordx4 %5, %17, off nt\n\t"
        "global_load_dwordx4 %6, %18, off nt\n\t"
        "global_load_dwordx4 %7, %19, off nt\n\t"
        "global_load_dwordx4 %8, %20, off nt\n\t"
        "global_load_dwordx4 %9, %21, off nt\n\t"
        "global_load_dwordx4 %10, %22, off nt\n\t"
        "global_load_dwordx4 %11, %23, off nt\n\t"
        "s_waitcnt vmcnt(0)"
        : "=&v"(m[0]), "=&v"(m[1]), "=&v"(m[2]), "=&v"(m[3]),
          "=&v"(r[0]), "=&v"(r[1]), "=&v"(r[2]), "=&v"(r[3]),
          "=&v"(e[0]), "=&v"(e[1]), "=&v"(e[2]), "=&v"(e[3])
        : "v"(m0p), "v"(m1p), "v"(m2p), "v"(m3p),
          "v"(r0p), "v"(r1p), "v"(r2p), "v"(r3p),
          "v"(e0p), "v"(e1p), "v"(e2p), "v"(e3p)
        : "memory");

    float kl = 0.f;
#pragma unroll
    for (int it = 0; it < EW_ITERS; ++it) {
        ushort w[4];
#pragma unroll
        for (int j = 0; j < 4; ++j) {
            float mm  = m[it][j];
            float sig = softplus_fast(r[it][j]);
            w[j] = f2bf(fmaf(sig, e[it][j], mm));
            kl += fmaf(50.f, fmaf(sig, sig, mm * mm), KL_C0 - __logf(sig));
        }
        ushortx4 packed = { w[0], w[1], w[2], w[3] };
        ((ushortx4*)wbf)[t + it * STRIDE] = packed;   // caching: L2/L3 holds for gemm
    }

#pragma unroll
    for (int off = 32; off; off >>= 1) kl += __shfl_down(kl, off);
    __shared__ float wsum[4];
    if ((threadIdx.x & 63) == 0) wsum[threadIdx.x >> 6] = kl;
    __syncthreads();
    if (threadIdx.x == 0)
        partials[blockIdx.x] = wsum[0] + wsum[1] + wsum[2] + wsum[3];
}

// ---------------- Kernel 2: x f32 -> bf16 -----------------------------------
__global__ __launch_bounds__(256) void xconv_kernel(
    const float* __restrict__ x, ushort* __restrict__ xb)
{
    int i = blockIdx.x * blockDim.x + threadIdx.x;
    float4 v = ((const float4*)x)[i];
    ushortx4 o = { f2bf(v.x), f2bf(v.y), f2bf(v.z), f2bf(v.w) };
    ((ushortx4*)xb)[i] = o;
}

// ---------------- Kernel 3: split-K bf16 MFMA GEMM partials ------------------
// (verified R9 form, unchanged)
__global__ __launch_bounds__(256, 4) void gemm_kernel(
    const ushort* __restrict__ A, const ushort* __restrict__ B,
    float* __restrict__ Cpart)
{
    __shared__ ushort As[64 * 64];   // 8 KB, linear (swizzled content)
    __shared__ ushort Bs[64 * 64];

    const int tid  = threadIdx.x;
    const int m0   = blockIdx.y * 64;
    const int n0   = blockIdx.x * 64;
    const int kz   = blockIdx.z;
    const int kb   = kz * KLEN;
    const int wid  = tid >> 6;
    const int lane = tid & 63;
    const int wm   = wid >> 1;
    const int wn   = wid & 1;

    floatx4 acc[2][2] = {};

    const int srow  = tid >> 3;
    const int scol8 = (tid & 7) ^ (srow & 7);   // swizzled source granule
    const ushort* Ag0 = A + (size_t)(m0 + srow) * IN_F + kb + scol8 * 8;
    const ushort* Ag1 = A + (size_t)(m0 + 32 + srow) * IN_F + kb + scol8 * 8;
    const ushort* Bg0 = B + (size_t)(n0 + srow) * IN_F + kb + scol8 * 8;
    const ushort* Bg1 = B + (size_t)(n0 + 32 + srow) * IN_F + kb + scol8 * 8;
    char* AsB = (char*)As + (tid & 192) * 16;   // wave-uniform dest base
    char* BsB = (char*)Bs + (tid & 192) * 16;

    const int hi = lane >> 4;
    const int lr = lane & 15;
    const int lx = lr & 7;

    for (int k0 = 0; k0 < KLEN; k0 += 64) {
        __syncthreads();
        __builtin_amdgcn_global_load_lds((GlbV*)(Ag0 + k0), (LdsV*)(AsB),        16, 0, 0);
        __builtin_amdgcn_global_load_lds((GlbV*)(Ag1 + k0), (LdsV*)(AsB + 4096), 16, 0, 0);
        __builtin_amdgcn_global_load_lds((GlbV*)(Bg0 + k0), (LdsV*)(BsB),        16, 0, 0);
        __builtin_amdgcn_global_load_lds((GlbV*)(Bg1 + k0), (LdsV*)(BsB + 4096), 16, 0, 0);
        __syncthreads();
#pragma unroll
        for (int s = 0; s < 2; ++s) {
            const int kkq = s * 4 + hi;
            const int cs  = ((kkq ^ lx) << 4);
            shortx8 af[2], bfr[2];
#pragma unroll
            for (int i = 0; i < 2; ++i) {
                const int rowA = wm * 32 + i * 16 + lr;
                af[i] = *(const shortx8*)((char*)As + rowA * 128 + cs);
            }
#pragma unroll
            for (int j = 0; j < 2; ++j) {
                const int rowB = wn * 32 + j * 16 + lr;
                bfr[j] = *(const shortx8*)((char*)Bs + rowB * 128 + cs);
            }
#pragma unroll
            for (int i = 0; i < 2; ++i)
#pragma unroll
                for (int j = 0; j < 2; ++j)
                    acc[i][j] = __builtin_amdgcn_mfma_f32_16x16x32_bf16(
                        af[i], bfr[j], acc[i][j], 0, 0, 0);
        }
    }

    // partial-C store
    float* Cp = Cpart + (size_t)kz * BATCH * OUT_F;
#pragma unroll
    for (int j = 0; j < 2; ++j) {
        const int nn = n0 + wn * 32 + j * 16 + lr;
#pragma unroll
        for (int i = 0; i < 2; ++i) {
            const int mbase = m0 + wm * 32 + i * 16 + hi * 4;
#pragma unroll
            for (int q = 0; q < 4; ++q)
                Cp[(size_t)(mbase + q) * OUT_F + nn] = acc[i][j][q];
        }
    }
}

// ---------------- Kernel 4: combine partials + bias + final KL ---------------
// (verified R10 form, unchanged)
__global__ __launch_bounds__(256) void combine_kernel(
    const float* __restrict__ Cpart,
    const float* __restrict__ bias_mu, const float* __restrict__ bias_rho,
    const float* __restrict__ eps_b, float* __restrict__ out,
    const float* __restrict__ partials, float* __restrict__ kl_out)
{
    const int i  = blockIdx.x * 256 + threadIdx.x;
    const size_t NP = (size_t)BATCH * OUT_F;
    floatx4 s = __builtin_nontemporal_load(((const floatx4*)Cpart) + i);
    s += __builtin_nontemporal_load(((const floatx4*)(Cpart + NP)) + i);
    s += __builtin_nontemporal_load(((const floatx4*)(Cpart + 2 * NP)) + i);
    s += __builtin_nontemporal_load(((const floatx4*)(Cpart + 3 * NP)) + i);
    const int o = (i * 4) & (OUT_F - 1);
    floatx4 bm = *(const floatx4*)(bias_mu + o);
    floatx4 br = *(const floatx4*)(bias_rho + o);
    floatx4 be = *(const floatx4*)(eps_b + o);
    floatx4 r;
#pragma unroll
    for (int j = 0; j < 4; ++j)
        r[j] = s[j] + fmaf(softplus_fast(br[j]), be[j], bm[j]);
    ((floatx4*)out)[i] = r;

    if (blockIdx.x == 0) {
        float kl = 0.f;
#pragma unroll
        for (int it = 0; it < EW_BLOCKS / 256; ++it)
            kl += partials[threadIdx.x + it * 256];
#pragma unroll
        for (int off = 32; off; off >>= 1) kl += __shfl_down(kl, off);
        __shared__ float wsum[4];
        if ((threadIdx.x & 63) == 0) wsum[threadIdx.x >> 6] = kl;
        __syncthreads();
        if (threadIdx.x == 0)
            *kl_out = wsum[0] + wsum[1] + wsum[2] + wsum[3];
    }
}

extern "C" void kernel_launch(void* const* d_in, const int* in_sizes, int n_in,
                              void* d_out, int out_size, void* d_ws, size_t ws_size,
                              hipStream_t stream) {
    const float* x     = (const float*)d_in[0];
    const float* w_mu  = (const float*)d_in[1];
    const float* w_rho = (const float*)d_in[2];
    const float* b_mu  = (const float*)d_in[3];
    const float* b_rho = (const float*)d_in[4];
    const float* eps_w = (const float*)d_in[5];
    const float* eps_b = (const float*)d_in[6];
    // d_in[7]=prior_mu (zeros), d_in[8]=prior_sigma (0.1): folded constants.

    float* out = (float*)d_out;
    const size_t KL_IDX = (size_t)BATCH * OUT_F;

    ushort* w_bf     = (ushort*)d_ws;                                     // 32 MB
    ushort* x_bf     = (ushort*)((char*)d_ws + (size_t)OUT_F * IN_F * 2); // 2 MB
    float*  Cpart    = (float*)((char*)x_bf + (size_t)BATCH * IN_F * 2);  // 16 MB
    float*  partials = (float*)((char*)Cpart
                         + (size_t)KSPLIT * BATCH * OUT_F * 4);           // 16 KB

    // weight sample + KL partials (asm-forced MLP-12 NT loads)
    ew_kernel<<<EW_BLOCKS, EW_THREADS, 0, stream>>>(
        w_mu, w_rho, eps_w, w_bf, partials);
    // x -> bf16
    xconv_kernel<<<(BATCH * IN_F / 4) / 256, 256, 0, stream>>>(x, x_bf);
    // split-K GEMM partials (1024 blocks = 4/CU)
    dim3 grid(OUT_F / 64, BATCH / 64, KSPLIT);
    gemm_kernel<<<grid, 256, 0, stream>>>(x_bf, w_bf, Cpart);
    // combine + bias + final KL
    combine_kernel<<<(BATCH * OUT_F / 4) / 256, 256, 0, stream>>>(
        Cpart, b_mu, b_rho, eps_b, out, partials, out + KL_IDX);
}